// Round 14
// baseline (12340.248 us; speedup 1.0000x reference)
//
#include <hip/hip_runtime.h>
#include <math.h>

#define NBLK 256
#define NTHR 512
#define GATHER 255

// ws float offsets (cross-block data via device-scope sc1 ops)
#define OFF_HX    0               // [8][1024] f32 (epilogue only, written at t=255)
#define OFF_HXH   8192            // [8][512] u32 bf16x2 of hx (A staging)
#define OFF_H0    12288           // [8][1024] f32
#define OFF_CTX   20480           // [8][1024] f32
#define OFF_Z     28672           // [4][8][1024] f32
#define OFF_KBH   61440           // [t][8 b][512 u32] bf16x2 (32 u32 per head)
#define OFF_VBH   (OFF_KBH + 1048576)
#define OFF_FLAGS (OFF_VBH + 1048576)  // 256 arrive slots(16u) + 8 go lines(16u) + 128 ctx flags(16u)
#define FLG_U32   (4096 + 128 + 2048)

// LDS float offsets
#define S_WG    0                // 32768 (128KB): 16 gate rows x 2048
#define S_STAGE 32768            // 4096: hx staging (A) / z staging (BCD) / PV partials
#define S_CX    36864            // 1024: replicated cell state, batch blk>>4 (blk<128)
#define S_H0L   37888            // 1024: local h0
#define S_Q     38912            // 64
#define S_PS    38976            // 256: softmax p
#define S_RED   39232            // 16
#define S_R2    39248            // 16
#define S_EH    39264            // 32: h0 slice for E [2 b][16 r]
#define S_ZX    39296            // 128: z exchange [16 h][8 b]
#define S_KVX   39424            // 64: kv exchange [8 hh][8 b]
#define LDS_FLOATS 39488
#define LDS_BYTES  (LDS_FLOATS * 4)   // 157952 <= 163840

typedef unsigned long long u64;
union F2U { u64 u; float2 f; };

__device__ __forceinline__ float ld1(const float* p) {
    return __hip_atomic_load(const_cast<float*>(p), __ATOMIC_RELAXED, __HIP_MEMORY_SCOPE_AGENT);
}
__device__ __forceinline__ void st1(float* p, float v) {
    __hip_atomic_store(p, v, __ATOMIC_RELAXED, __HIP_MEMORY_SCOPE_AGENT);
}
__device__ __forceinline__ unsigned ldu(const unsigned* p) {
    return __hip_atomic_load(const_cast<unsigned*>(p), __ATOMIC_RELAXED, __HIP_MEMORY_SCOPE_AGENT);
}
__device__ __forceinline__ void stu(unsigned* p, unsigned v) {
    __hip_atomic_store(p, v, __ATOMIC_RELAXED, __HIP_MEMORY_SCOPE_AGENT);
}
__device__ __forceinline__ u64 ldu64(const unsigned* p) {
    return __hip_atomic_load(reinterpret_cast<u64*>(const_cast<unsigned*>(p)),
                             __ATOMIC_RELAXED, __HIP_MEMORY_SCOPE_AGENT);
}
__device__ __forceinline__ float2 ld2(const float* p) {
    F2U c; c.u = __hip_atomic_load(reinterpret_cast<u64*>(const_cast<float*>(p)),
                                   __ATOMIC_RELAXED, __HIP_MEMORY_SCOPE_AGENT);
    return c.f;
}
__device__ __forceinline__ void st2(float* p, float2 v) {
    F2U c; c.f = v;
    __hip_atomic_store(reinterpret_cast<u64*>(p), c.u,
                       __ATOMIC_RELAXED, __HIP_MEMORY_SCOPE_AGENT);
}
__device__ __forceinline__ float4 ld4(const float* p) {
    float2 a = ld2(p), b = ld2(p + 2);
    return make_float4(a.x, a.y, b.x, b.y);
}
__device__ __forceinline__ float dot4(const float4 a, const float4 b) {
    return a.x*b.x + a.y*b.y + a.z*b.z + a.w*b.w;
}
__device__ __forceinline__ unsigned pack_bf16(float lo, float hi) {
    unsigned ul = __builtin_bit_cast(unsigned, lo);
    ul = (ul + 0x7FFFu + ((ul >> 16) & 1u)) >> 16;
    unsigned uh = __builtin_bit_cast(unsigned, hi);
    uh = (uh + 0x7FFFu + ((uh >> 16) & 1u)) >> 16;
    return ul | (uh << 16);
}
__device__ __forceinline__ float2 unpack_bf16(unsigned u) {
    return make_float2(__builtin_bit_cast(float, u << 16),
                       __builtin_bit_cast(float, u & 0xFFFF0000u));
}

// Split barrier: arrive (own slot) / wait (GATHER block polls all, releases
// 8 go lines; others poll their line). Monotonic u32 eras, memset per launch.
__device__ __forceinline__ void arrive(unsigned* flags, int blk, unsigned bc) {
    __syncthreads();                 // drains outstanding sc1 stores
    if (threadIdx.x == 0) stu(flags + blk * 16, bc);
}
__device__ __forceinline__ void waitbar(unsigned* flags, unsigned* golines,
                                        unsigned bc, int blk) {
    if (blk == GATHER) {
        if (threadIdx.x < 256)
            while (ldu(flags + threadIdx.x * 16) < bc) __builtin_amdgcn_s_sleep(4);
        __syncthreads();
        if (threadIdx.x < 8) stu(golines + threadIdx.x * 16, bc);
    } else {
        if (threadIdx.x == 0)
            while (ldu(golines + (blk >> 5) * 16) < bc) __builtin_amdgcn_s_sleep(4);
    }
    __syncthreads();
}

__global__ __launch_bounds__(NTHR, 1)
void qlstm_kernel(const float* __restrict__ x,  const float* __restrict__ Wg,
                  const float* __restrict__ bg, const float* __restrict__ lng,
                  const float* __restrict__ lnb,const float* __restrict__ Wq,
                  const float* __restrict__ Wk, const float* __restrict__ Wv,
                  const float* __restrict__ bq, const float* __restrict__ bk,
                  const float* __restrict__ bv, const float* __restrict__ Wo,
                  const float* __restrict__ bo, float* __restrict__ out,
                  float* __restrict__ ws)
{
    extern __shared__ float lds[];
    const int blk = blockIdx.x, tid = threadIdx.x;
    const int w = tid >> 6, l = tid & 63;

    float* hx   = ws + OFF_HX;
    unsigned* hxh = (unsigned*)(ws + OFF_HXH);
    float* h0g  = ws + OFF_H0;
    float* ctx  = ws + OFF_CTX;
    float* z    = ws + OFF_Z;
    unsigned* Kbh = (unsigned*)(ws + OFF_KBH);
    unsigned* Vbh = (unsigned*)(ws + OFF_VBH);
    unsigned* flags   = (unsigned*)(ws + OFF_FLAGS);
    unsigned* golines = flags + 4096;
    unsigned* cflg    = golines + 128;
    unsigned bc = 1;

    // ---- Wg slice (16 rows x 2048) -> LDS ----
    {
        const float* wsrc = Wg + (size_t)blk * 32768;
        #pragma unroll
        for (int j = 0; j < 16; ++j) {
            const int fi = j * 512 + tid;
            *(float4*)(lds + S_WG + fi * 4) = *(const float4*)(wsrc + fi * 4);
        }
    }
    // ---- K/V rows (1 per wave) in VGPRs; whole block same matrix ----
    const int kv_mat = blk >> 7;                   // 0=K (blk<128), 1=V
    const int kv_h   = (blk & 127) * 8 + w;
    const float* kv_wrow = (kv_mat ? Wv : Wk) + (size_t)kv_h * 1024;
    float4 wkv[4];
    #pragma unroll
    for (int i = 0; i < 4; ++i) wkv[i] = *(const float4*)(kv_wrow + i * 256 + l * 4);
    const float kv_bias = (kv_mat ? bv : bk)[kv_h];
    // ---- gate rows (gate g, rows hbase+2w, +2w+1) ----
    const int g     = blk >> 6;
    const int hbase = (blk & 63) * 16;
    const int h0r   = hbase + 2 * w;
    const float bg0 = bg[g * 1024 + h0r], bg1 = bg[g * 1024 + h0r + 1];
    // ---- LN params ----
    float lnw0[4], lnw1[4], lnb0v[4], lnb1v[4];
    #pragma unroll
    for (int g2 = 0; g2 < 4; ++g2) {
        lnw0[g2] = lng[g2 * 1024 + tid];       lnb0v[g2] = lnb[g2 * 1024 + tid];
        lnw1[g2] = lng[g2 * 1024 + 512 + tid]; lnb1v[g2] = lnb[g2 * 1024 + 512 + tid];
    }
    // ---- E split: rows rg*16..+15 (wave pair er0,er0+1), batches bp*2, bp*2+1 ----
    const int rg = blk >> 2, bp = blk & 3;
    const int er0 = rg * 16 + 2 * w;
    const int eb0 = bp * 2, eb1 = eb0 + 1;
    const float bor0 = bo[er0], bor1 = bo[er0 + 1];
    // ---- attention identity (blk<128): batch, head ----
    const int ab = blk >> 4, anh = blk & 15;
    const bool h0_writer = (blk < 128) && ((blk & 15) == 0);
    // q-proj thread mapping (blk<128): row dh of head anh, k-chunk qks
    const int qdh = tid >> 3, qks = tid & 7;
    const float q_bias = (blk < 128) ? bq[anh * 64 + qdh] : 0.f;

    // ---- init: zero hxh (read at t=0), zero replicated cx ----
    { const int gi = blk * NTHR + tid; if (gi < 4096) stu(hxh + gi, 0u); }
    if (tid < 256) *(float4*)(lds + S_CX + tid * 4) = make_float4(0,0,0,0);
    arrive(flags, blk, bc);          // era 1: initial hxh ready

    for (int t = 0; t < 256; ++t) {
        // ===== x-part of gate GEMV (independent; overlaps hx-bar wait) =====
        float a0[8], a1[8];
        {
            const float* xt = x + (size_t)t * 8192;
            #pragma unroll
            for (int b = 0; b < 8; ++b) { a0[b] = 0.f; a1[b] = 0.f; }
            #pragma unroll
            for (int i = 0; i < 4; ++i) {
                const int k = i * 256 + l * 4;
                const float4 w0 = *(const float4*)(lds + S_WG + (2*w)   * 2048 + k);
                const float4 w1 = *(const float4*)(lds + S_WG + (2*w+1) * 2048 + k);
                #pragma unroll
                for (int b = 0; b < 8; ++b) {
                    const float4 a = *(const float4*)(xt + b * 1024 + k);
                    a0[b] += dot4(w0, a); a1[b] += dot4(w1, a);
                }
            }
        }
        waitbar(flags, golines, bc, blk);   // hx(t-1) visible

        // ===== Phase A: hx-part gate GEMV (bf16-staged) + KV proj =====
        {
            float akv[8];
            #pragma unroll
            for (int b = 0; b < 8; ++b) akv[b] = 0.f;
            unsigned hregu[8];
            #pragma unroll
            for (int c = 0; c < 2; ++c)
                #pragma unroll
                for (int j = 0; j < 4; ++j) {
                    const int ix = j * 512 + tid;              // 0..2047 per chunk
                    const int b = ix >> 8, p = ix & 255;
                    hregu[c * 4 + j] = ldu(hxh + b * 512 + c * 256 + p);
                }
            #pragma unroll
            for (int c = 0; c < 2; ++c) {
                if (c) __syncthreads();
                #pragma unroll
                for (int j = 0; j < 4; ++j) {
                    const int ix = j * 512 + tid;
                    const int b = ix >> 8, p = ix & 255;
                    *(float2*)(lds + S_STAGE + b * 512 + p * 2) = unpack_bf16(hregu[c * 4 + j]);
                }
                __syncthreads();
                #pragma unroll
                for (int ii = 0; ii < 2; ++ii) {
                    const int k = ii * 256 + l * 4;
                    const float4 w0 = *(const float4*)(lds + S_WG + (2*w)   * 2048 + 1024 + c * 512 + k);
                    const float4 w1 = *(const float4*)(lds + S_WG + (2*w+1) * 2048 + 1024 + c * 512 + k);
                    const float4 wk = wkv[c * 2 + ii];
                    #pragma unroll
                    for (int b = 0; b < 8; ++b) {
                        const float4 a = *(const float4*)(lds + S_STAGE + b * 512 + k);
                        a0[b] += dot4(w0, a); a1[b] += dot4(w1, a); akv[b] += dot4(wk, a);
                    }
                }
            }
            #pragma unroll
            for (int o = 1; o < 64; o <<= 1)
                #pragma unroll
                for (int b = 0; b < 8; ++b) {
                    a0[b]  += __shfl_xor(a0[b], o);
                    a1[b]  += __shfl_xor(a1[b], o);
                    akv[b] += __shfl_xor(akv[b], o);
                }
            if (l == 0) {
                #pragma unroll
                for (int b = 0; b < 8; ++b) {
                    lds[S_ZX + (2*w)   * 8 + b] = a0[b] + bg0;
                    lds[S_ZX + (2*w+1) * 8 + b] = a1[b] + bg1;
                    lds[S_KVX + w * 8 + b]      = akv[b] + kv_bias;
                }
            }
            __syncthreads();
            if (tid < 128) {                         // coalesced z store
                const int h = tid & 15, b2 = tid >> 4;
                st1(z + (size_t)(g * 8 + b2) * 1024 + hbase + h, lds[S_ZX + h * 8 + b2]);
            } else if (tid < 160 && t > 0) {         // packed bf16 KV store
                const int j = tid - 128;
                const int b2 = j >> 2, hp = j & 3;
                unsigned* dst = kv_mat ? Vbh : Kbh;
                stu(dst + ((size_t)(t - 1) * 8 + b2) * 512 + (blk & 127) * 4 + hp,
                    pack_bf16(lds[S_KVX + (2*hp) * 8 + b2], lds[S_KVX + (2*hp+1) * 8 + b2]));
            }
        }
        ++bc; arrive(flags, blk, bc);
        waitbar(flags, golines, bc, blk);   // z (and KV) ready

        // ===== Phase BCD: LN+cell + own-head q-proj + attention (blk<128) =====
        if (blk < 128) {
            {   // stage z[4][ab][1024] — reg-prefetch then store
                float2 zreg[4];
                #pragma unroll
                for (int j = 0; j < 4; ++j) {
                    const int idx = j * 512 + tid;
                    const int g2 = idx >> 9, off2 = idx & 511;
                    zreg[j] = ld2(z + ((size_t)g2 * 8 + ab) * 1024 + off2 * 2);
                }
                #pragma unroll
                for (int j = 0; j < 4; ++j)
                    *(float2*)(lds + S_STAGE + (j * 512 + tid) * 2) = zreg[j];
            }
            __syncthreads();
            const int gt = w >> 1, hf = w & 1;
            float s = 0.f, q2s = 0.f;
            #pragma unroll
            for (int j = 0; j < 8; ++j) {
                const float v = lds[S_STAGE + gt * 1024 + hf * 512 + j * 64 + l];
                s += v; q2s += v * v;
            }
            #pragma unroll
            for (int o = 1; o < 64; o <<= 1) { s += __shfl_xor(s, o); q2s += __shfl_xor(q2s, o); }
            if (l == 0) { lds[S_RED + w] = s; lds[S_R2 + w] = q2s; }
            __syncthreads();
            float mean[4], rstd[4];
            #pragma unroll
            for (int g2 = 0; g2 < 4; ++g2) {
                const float ss = lds[S_RED + 2*g2] + lds[S_RED + 2*g2 + 1];
                const float qq = lds[S_R2  + 2*g2] + lds[S_R2  + 2*g2 + 1];
                const float m = ss * (1.f / 1024.f);
                mean[g2] = m;
                rstd[g2] = rsqrtf(qq * (1.f / 1024.f) - m * m + 1e-5f);
            }
            {   // h = tid
                float zv[4];
                #pragma unroll
                for (int g2 = 0; g2 < 4; ++g2)
                    zv[g2] = (lds[S_STAGE + g2 * 1024 + tid] - mean[g2]) * rstd[g2] * lnw0[g2] + lnb0v[g2];
                const float f  = 1.f / (1.f + __expf(-zv[0]));
                const float ii = 1.f / (1.f + __expf(-zv[1]));
                const float gg = tanhf(zv[2]);
                const float oo = 1.f / (1.f + __expf(-zv[3]));
                const float c  = f * lds[S_CX + tid] + ii * gg;
                lds[S_CX + tid] = c;
                const float ho = oo * tanhf(c);
                lds[S_H0L + tid] = ho;
                if (h0_writer) st1(h0g + ab * 1024 + tid, ho);
            }
            {   // h = tid + 512
                float zv[4];
                #pragma unroll
                for (int g2 = 0; g2 < 4; ++g2)
                    zv[g2] = (lds[S_STAGE + g2 * 1024 + 512 + tid] - mean[g2]) * rstd[g2] * lnw1[g2] + lnb1v[g2];
                const float f  = 1.f / (1.f + __expf(-zv[0]));
                const float ii = 1.f / (1.f + __expf(-zv[1]));
                const float gg = tanhf(zv[2]);
                const float oo = 1.f / (1.f + __expf(-zv[3]));
                const float c  = f * lds[S_CX + 512 + tid] + ii * gg;
                lds[S_CX + 512 + tid] = c;
                const float ho = oo * tanhf(c);
                lds[S_H0L + 512 + tid] = ho;
                if (h0_writer) st1(h0g + ab * 1024 + 512 + tid, ho);
            }
            __syncthreads();
            {   // q-proj for own head: 64 rows, streamed Wq (L2-resident)
                const float* wrow = Wq + (size_t)(anh * 64 + qdh) * 1024;
                float qa = 0.f;
                #pragma unroll 8
                for (int j = 0; j < 32; ++j) {
                    const int k = j * 32 + qks * 4;
                    qa += dot4(*(const float4*)(wrow + k), *(const float4*)(lds + S_H0L + k));
                }
                qa += __shfl_xor(qa, 1); qa += __shfl_xor(qa, 2); qa += __shfl_xor(qa, 4);
                if (qks == 0) lds[S_Q + qdh] = (qa + q_bias) * 0.125f;
            }
            __syncthreads();
            if (t > 0) {
                // QK: scatter per-position (good ILP), bf16 K rows
                float sc = -1e30f;
                if (tid < t) {
                    const unsigned* kr = Kbh + ((size_t)tid * 8 + ab) * 512 + anh * 32;
                    float d = 0.f;
                    #pragma unroll
                    for (int j = 0; j < 16; ++j) {
                        F2U c; c.u = ldu64(kr + j * 2);
                        const float2 p0 = unpack_bf16((unsigned)(c.u & 0xFFFFFFFFu));
                        const float2 p1 = unpack_bf16((unsigned)(c.u >> 32));
                        d += p0.x*lds[S_Q + j*4]   + p0.y*lds[S_Q + j*4+1]
                           + p1.x*lds[S_Q + j*4+2] + p1.y*lds[S_Q + j*4+3];
                    }
                    sc = d;
                }
                float mx = sc;
                #pragma unroll
                for (int o = 1; o < 64; o <<= 1) mx = fmaxf(mx, __shfl_xor(mx, o));
                if (l == 0) lds[S_RED + w] = mx;
                __syncthreads();
                mx = lds[S_RED];
                #pragma unroll
                for (int j = 1; j < 8; ++j) mx = fmaxf(mx, lds[S_RED + j]);
                const float p = (tid < t) ? __expf(sc - mx) : 0.f;
                if (tid < 256) lds[S_PS + tid] = p;
                float ps = p;
                #pragma unroll
                for (int o = 1; o < 64; o <<= 1) ps += __shfl_xor(ps, o);
                if (l == 0) lds[S_R2 + w] = ps;
                __syncthreads();
                float tot = lds[S_R2];
                #pragma unroll
                for (int j = 1; j < 8; ++j) tot += lds[S_R2 + j];
                const float inv = 1.f / tot;
                // PV: 4x unrolled, dual accumulators, bf16 V
                const int dh2 = tid & 31, ss2 = tid >> 5;
                const unsigned* vbase = Vbh + (size_t)ab * 512 + anh * 32 + dh2;
                float cax0 = 0.f, cay0 = 0.f, cax1 = 0.f, cay1 = 0.f;
                int s2 = ss2;
                for (; s2 + 48 < t; s2 += 64) {
                    const float2 va = unpack_bf16(ldu(vbase + (size_t)(s2)      * 4096));
                    const float2 vb = unpack_bf16(ldu(vbase + (size_t)(s2 + 16) * 4096));
                    const float2 vc = unpack_bf16(ldu(vbase + (size_t)(s2 + 32) * 4096));
                    const float2 vd = unpack_bf16(ldu(vbase + (size_t)(s2 + 48) * 4096));
                    const float pa = lds[S_PS + s2],      pb = lds[S_PS + s2 + 16];
                    const float pc = lds[S_PS + s2 + 32], pd = lds[S_PS + s2 + 48];
                    cax0 += pa * va.x; cay0 += pa * va.y;
                    cax1 += pb * vb.x; cay1 += pb * vb.y;
                    cax0 += pc * vc.x; cay0 += pc * vc.y;
                    cax1 += pd * vd.x; cay1 += pd * vd.y;
                }
                for (; s2 < t; s2 += 16) {
                    const float pp = lds[S_PS + s2];
                    const float2 v2 = unpack_bf16(ldu(vbase + (size_t)s2 * 4096));
                    cax0 += pp * v2.x; cay0 += pp * v2.y;
                }
                *(float2*)(lds + S_STAGE + tid * 2) = make_float2(cax0 + cax1, cay0 + cay1);
                __syncthreads();
                if (tid < 64) {
                    float v = 0.f;
                    #pragma unroll
                    for (int j = 0; j < 16; ++j) v += lds[S_STAGE + j * 64 + tid];
                    st1(ctx + ab * 1024 + anh * 64 + tid, v * inv);
                }
            }
            // producer flag: ctx[ab][anh] (and h0g for anh==0) drained by syncthreads
            __syncthreads();
            if (tid == 0) stu(cflg + blk * 16, (unsigned)(t + 1));
        }

        // ===== E wait: poll the 32 producer flags for batches eb0, eb1 =====
        {
            if (tid < 32) {
                const int pb = (tid < 16) ? eb0 : eb1;
                const unsigned* f = cflg + (pb * 16 + (tid & 15)) * 16;
                while (ldu(f) < (unsigned)(t + 1)) __builtin_amdgcn_s_sleep(2);
            }
            __syncthreads();
        }

        // ===== Phase E: out-proj (16 rows x 2 batches, direct ctx reads) =====
        {
            if (tid < 16) {     // h0 slice: [2 b][16 r] into S_EH
                const int bsel = tid >> 3, hp = tid & 7;
                *(float2*)(lds + S_EH + bsel * 16 + hp * 2) =
                    ld2(h0g + (size_t)(eb0 + bsel) * 1024 + rg * 16 + hp * 2);
            }
            float o00 = 0.f, o01 = 0.f, o10 = 0.f, o11 = 0.f;  // row(2) x batch(2)
            if (t > 0) {
                float4 c0r[4], c1r[4];
                #pragma unroll
                for (int i = 0; i < 4; ++i) {
                    const int k = i * 256 + l * 4;
                    c0r[i] = ld4(ctx + (size_t)eb0 * 1024 + k);
                    c1r[i] = ld4(ctx + (size_t)eb1 * 1024 + k);
                }
                #pragma unroll
                for (int i = 0; i < 4; ++i) {
                    const int k = i * 256 + l * 4;
                    const float4 w0 = *(const float4*)(Wo + (size_t)er0 * 1024 + k);
                    const float4 w1 = *(const float4*)(Wo + (size_t)(er0+1) * 1024 + k);
                    o00 += dot4(w0, c0r[i]); o01 += dot4(w0, c1r[i]);
                    o10 += dot4(w1, c0r[i]); o11 += dot4(w1, c1r[i]);
                }
                #pragma unroll
                for (int o = 1; o < 64; o <<= 1) {
                    o00 += __shfl_xor(o00, o); o01 += __shfl_xor(o01, o);
                    o10 += __shfl_xor(o10, o); o11 += __shfl_xor(o11, o);
                }
            }
            __syncthreads();
            if (l == 0) {
                const float h00 = lds[S_EH + 2*w],      h10 = lds[S_EH + 2*w + 1];
                const float h01 = lds[S_EH + 16 + 2*w], h11 = lds[S_EH + 16 + 2*w + 1];
                const float v00 = (t > 0) ? h00 + o00 + bor0 : h00;
                const float v10 = (t > 0) ? h10 + o10 + bor1 : h10;
                const float v01 = (t > 0) ? h01 + o01 + bor0 : h01;
                const float v11 = (t > 0) ? h11 + o11 + bor1 : h11;
                stu(hxh + eb0 * 512 + (er0 >> 1), pack_bf16(v00, v10));
                stu(hxh + eb1 * 512 + (er0 >> 1), pack_bf16(v01, v11));
                *(float2*)(out + (size_t)t * 8192 + eb0 * 1024 + er0) = make_float2(v00, v10);
                *(float2*)(out + (size_t)t * 8192 + eb1 * 1024 + er0) = make_float2(v01, v11);
                if (t == 255) {
                    st2(hx + eb0 * 1024 + er0, make_float2(v00, v10));
                    st2(hx + eb1 * 1024 + er0, make_float2(v01, v11));
                }
            }
        }
        ++bc; arrive(flags, blk, bc);       // hx(t) ready (waited at top of t+1)
    }
    waitbar(flags, golines, bc, blk);

    // epilogue: final cx (replicas) and hx
    if (h0_writer) {
        out[2097152 + 8192 + ab * 1024 + tid]       = lds[S_CX + tid];
        out[2097152 + 8192 + ab * 1024 + 512 + tid] = lds[S_CX + 512 + tid];
    }
    if (blk >= 136 && blk < 144) {
        const int b = blk - 136;
        out[2097152 + b * 1024 + tid]       = ld1(hx + b * 1024 + tid);
        out[2097152 + b * 1024 + 512 + tid] = ld1(hx + b * 1024 + 512 + tid);
    }
}

extern "C" void kernel_launch(void* const* d_in, const int* in_sizes, int n_in,
                              void* d_out, int out_size, void* d_ws, size_t ws_size,
                              hipStream_t stream) {
    const float* x   = (const float*)d_in[0];
    const float* Wg  = (const float*)d_in[1];
    const float* bg  = (const float*)d_in[2];
    const float* lng = (const float*)d_in[3];
    const float* lnb = (const float*)d_in[4];
    const float* Wq  = (const float*)d_in[5];
    const float* Wk  = (const float*)d_in[6];
    const float* Wv  = (const float*)d_in[7];
    const float* bq  = (const float*)d_in[8];
    const float* bk  = (const float*)d_in[9];
    const float* bv  = (const float*)d_in[10];
    const float* Wo  = (const float*)d_in[11];
    const float* bo  = (const float*)d_in[12];
    float* out = (float*)d_out;
    float* ws  = (float*)d_ws;

    static int attr_set = 0;
    if (!attr_set) {
        hipFuncSetAttribute((const void*)qlstm_kernel,
                            hipFuncAttributeMaxDynamicSharedMemorySize, LDS_BYTES);
        attr_set = 1;
    }
    // zero flags + go lines + ctx flags (graph-captured; deterministic per replay)
    hipMemsetAsync((char*)d_ws + (size_t)OFF_FLAGS * 4, 0, (size_t)FLG_U32 * 4, stream);

    void* args[] = { &x, &Wg, &bg, &lng, &lnb, &Wq, &Wk, &Wv,
                     &bq, &bk, &bv, &Wo, &bo, &out, &ws };
    hipLaunchCooperativeKernel((void*)qlstm_kernel, dim3(NBLK), dim3(NTHR),
                               args, LDS_BYTES, stream);
}

// Round 15
// 9712.309 us; speedup vs baseline: 1.2706x; 1.2706x over previous
//
#include <hip/hip_runtime.h>
#include <math.h>

#define NBLK 256
#define NTHR 512
#define GATHER 255

// ws float offsets (rewritten state via device-scope sc1; K/V write-once -> sc1 store, cached read)
#define OFF_HX    0               // [8][1024] f32
#define OFF_H0    8192            // [8][1024]
#define OFF_CTX   16384           // [8][1024]
#define OFF_Z     24576           // [4][8][1024]
#define OFF_KB    57344           // [256][8][1024] f32 (write-once per row)
#define OFF_VB    (OFF_KB + 2097152)
#define OFF_FLAGS (OFF_VB + 2097152)   // 256 arrive slots(16u) + 8 go lines(16u) + 128 ctx flags(16u)
#define FLG_U32   (4096 + 128 + 2048)

// LDS float offsets
#define S_WG    0                // 32768 (128KB): 16 gate rows x 2048
#define S_STAGE 32768            // 4096: hx staging (A) / z staging (BCD) / PV partials
#define S_CX    36864            // 1024: replicated cell state, batch blk>>4 (blk<128)
#define S_H0L   37888            // 1024: local h0
#define S_Q     38912            // 64
#define S_PS    38976            // 256: softmax p
#define S_RED   39232            // 16
#define S_R2    39248            // 16
#define S_EH    39264            // 32: h0 slice for E [2 b][16 r]
#define S_ZX    39296            // 128: z exchange [16 h][8 b]
#define S_KVX   39424            // 64: kv exchange [8 hh][8 b]
#define LDS_FLOATS 39488
#define LDS_BYTES  (LDS_FLOATS * 4)   // 157952 <= 163840

typedef unsigned long long u64;
union F2U { u64 u; float2 f; };

__device__ __forceinline__ float ld1(const float* p) {
    return __hip_atomic_load(const_cast<float*>(p), __ATOMIC_RELAXED, __HIP_MEMORY_SCOPE_AGENT);
}
__device__ __forceinline__ void st1(float* p, float v) {
    __hip_atomic_store(p, v, __ATOMIC_RELAXED, __HIP_MEMORY_SCOPE_AGENT);
}
__device__ __forceinline__ unsigned ldu(const unsigned* p) {
    return __hip_atomic_load(const_cast<unsigned*>(p), __ATOMIC_RELAXED, __HIP_MEMORY_SCOPE_AGENT);
}
__device__ __forceinline__ void stu(unsigned* p, unsigned v) {
    __hip_atomic_store(p, v, __ATOMIC_RELAXED, __HIP_MEMORY_SCOPE_AGENT);
}
__device__ __forceinline__ float2 ld2(const float* p) {
    F2U c; c.u = __hip_atomic_load(reinterpret_cast<u64*>(const_cast<float*>(p)),
                                   __ATOMIC_RELAXED, __HIP_MEMORY_SCOPE_AGENT);
    return c.f;
}
__device__ __forceinline__ void st2(float* p, float2 v) {
    F2U c; c.f = v;
    __hip_atomic_store(reinterpret_cast<u64*>(p), c.u,
                       __ATOMIC_RELAXED, __HIP_MEMORY_SCOPE_AGENT);
}
__device__ __forceinline__ float4 ld4(const float* p) {
    float2 a = ld2(p), b = ld2(p + 2);
    return make_float4(a.x, a.y, b.x, b.y);
}
__device__ __forceinline__ float dot4(const float4 a, const float4 b) {
    return a.x*b.x + a.y*b.y + a.z*b.z + a.w*b.w;
}

// Split barrier: arrive (own slot) / wait (GATHER block polls all, releases
// 8 go lines; others poll their line). Monotonic u32 eras, memset per launch.
__device__ __forceinline__ void arrive(unsigned* flags, int blk, unsigned bc) {
    __syncthreads();                 // drains outstanding sc1 stores
    if (threadIdx.x == 0) stu(flags + blk * 16, bc);
}
__device__ __forceinline__ void waitbar(unsigned* flags, unsigned* golines,
                                        unsigned bc, int blk) {
    if (blk == GATHER) {
        if (threadIdx.x < 256)
            while (ldu(flags + threadIdx.x * 16) < bc) __builtin_amdgcn_s_sleep(4);
        __syncthreads();
        if (threadIdx.x < 8) stu(golines + threadIdx.x * 16, bc);
    } else {
        if (threadIdx.x == 0)
            while (ldu(golines + (blk >> 5) * 16) < bc) __builtin_amdgcn_s_sleep(4);
    }
    __syncthreads();
}

__global__ __launch_bounds__(NTHR, 1)
void qlstm_kernel(const float* __restrict__ x,  const float* __restrict__ Wg,
                  const float* __restrict__ bg, const float* __restrict__ lng,
                  const float* __restrict__ lnb,const float* __restrict__ Wq,
                  const float* __restrict__ Wk, const float* __restrict__ Wv,
                  const float* __restrict__ bq, const float* __restrict__ bk,
                  const float* __restrict__ bv, const float* __restrict__ Wo,
                  const float* __restrict__ bo, float* __restrict__ out,
                  float* __restrict__ ws)
{
    extern __shared__ float lds[];
    const int blk = blockIdx.x, tid = threadIdx.x;
    const int w = tid >> 6, l = tid & 63;

    // One-time L1/L2 invalidate: clears any poison lines cached by the host's
    // 0xAA memset so later NORMAL (cached) reads of the write-once K/V region
    // can't hit stale data. K/V values are deterministic across graph replays,
    // so replay-held lines are value-identical (also cleared here anyway).
    __builtin_amdgcn_fence(__ATOMIC_ACQUIRE, "agent");

    float* hx  = ws + OFF_HX;   float* h0g = ws + OFF_H0;
    float* ctx = ws + OFF_CTX;  float* z   = ws + OFF_Z;
    float* Kb  = ws + OFF_KB;   float* Vb  = ws + OFF_VB;
    unsigned* flags   = (unsigned*)(ws + OFF_FLAGS);
    unsigned* golines = flags + 4096;
    unsigned* cflg    = golines + 128;
    unsigned bc = 1;

    // ---- Wg slice (16 rows x 2048) -> LDS ----
    {
        const float* wsrc = Wg + (size_t)blk * 32768;
        #pragma unroll
        for (int j = 0; j < 16; ++j) {
            const int fi = j * 512 + tid;
            *(float4*)(lds + S_WG + fi * 4) = *(const float4*)(wsrc + fi * 4);
        }
    }
    // ---- K/V rows (1 per wave) in VGPRs; whole block same matrix ----
    const int kv_mat = blk >> 7;                   // 0=K (blk<128), 1=V
    const int kv_h   = (blk & 127) * 8 + w;
    const float* kv_wrow = (kv_mat ? Wv : Wk) + (size_t)kv_h * 1024;
    float4 wkv[4];
    #pragma unroll
    for (int i = 0; i < 4; ++i) wkv[i] = *(const float4*)(kv_wrow + i * 256 + l * 4);
    const float kv_bias = (kv_mat ? bv : bk)[kv_h];
    // ---- gate rows (gate g, rows hbase+2w, +2w+1) ----
    const int g     = blk >> 6;
    const int hbase = (blk & 63) * 16;
    const int h0r   = hbase + 2 * w;
    const float bg0 = bg[g * 1024 + h0r], bg1 = bg[g * 1024 + h0r + 1];
    // ---- LN params ----
    float lnw0[4], lnw1[4], lnb0v[4], lnb1v[4];
    #pragma unroll
    for (int g2 = 0; g2 < 4; ++g2) {
        lnw0[g2] = lng[g2 * 1024 + tid];       lnb0v[g2] = lnb[g2 * 1024 + tid];
        lnw1[g2] = lng[g2 * 1024 + 512 + tid]; lnb1v[g2] = lnb[g2 * 1024 + 512 + tid];
    }
    // ---- E split: rows rg*16..+15 (wave pair er0,er0+1), batches bp*2, bp*2+1 ----
    const int rg = blk >> 2, bp = blk & 3;
    const int er0 = rg * 16 + 2 * w;
    const int eb0 = bp * 2, eb1 = eb0 + 1;
    const float bor0 = bo[er0], bor1 = bo[er0 + 1];
    // ---- attention identity (blk<128): batch, head ----
    const int ab = blk >> 4, anh = blk & 15;
    const bool h0_writer = (blk < 128) && ((blk & 15) == 0);
    // q-proj thread mapping (blk<128): row dh of head anh, k-chunk qks
    const int qdh = tid >> 3, qks = tid & 7;
    const float q_bias = (blk < 128) ? bq[anh * 64 + qdh] : 0.f;

    // ---- init: zero hx, zero replicated cx ----
    { const int gi = blk * NTHR + tid; if (gi < 8192) st1(hx + gi, 0.f); }
    if (tid < 256) *(float4*)(lds + S_CX + tid * 4) = make_float4(0,0,0,0);
    arrive(flags, blk, bc);          // era 1: initial hx ready

    for (int t = 0; t < 256; ++t) {
        // ===== x-part of gate GEMV (independent; overlaps hx-bar wait) =====
        float a0[8], a1[8];
        {
            const float* xt = x + (size_t)t * 8192;
            #pragma unroll
            for (int b = 0; b < 8; ++b) { a0[b] = 0.f; a1[b] = 0.f; }
            #pragma unroll
            for (int i = 0; i < 4; ++i) {
                const int k = i * 256 + l * 4;
                const float4 w0 = *(const float4*)(lds + S_WG + (2*w)   * 2048 + k);
                const float4 w1 = *(const float4*)(lds + S_WG + (2*w+1) * 2048 + k);
                #pragma unroll
                for (int b = 0; b < 8; ++b) {
                    const float4 a = *(const float4*)(xt + b * 1024 + k);
                    a0[b] += dot4(w0, a); a1[b] += dot4(w1, a);
                }
            }
        }
        waitbar(flags, golines, bc, blk);   // hx(t-1) visible

        // ===== Phase A: hx-part gate GEMV + KV proj =====
        {
            float akv[8];
            #pragma unroll
            for (int b = 0; b < 8; ++b) akv[b] = 0.f;
            float2 hreg[8];
            #pragma unroll
            for (int c = 0; c < 2; ++c)
                #pragma unroll
                for (int j = 0; j < 4; ++j) {
                    const int idx = j * 512 + tid;
                    const int b = idx >> 8, off2 = idx & 255;
                    hreg[c * 4 + j] = ld2(hx + b * 1024 + c * 512 + off2 * 2);
                }
            #pragma unroll
            for (int c = 0; c < 2; ++c) {
                if (c) __syncthreads();
                #pragma unroll
                for (int j = 0; j < 4; ++j)
                    *(float2*)(lds + S_STAGE + (j * 512 + tid) * 2) = hreg[c * 4 + j];
                __syncthreads();
                #pragma unroll
                for (int ii = 0; ii < 2; ++ii) {
                    const int k = ii * 256 + l * 4;
                    const float4 w0 = *(const float4*)(lds + S_WG + (2*w)   * 2048 + 1024 + c * 512 + k);
                    const float4 w1 = *(const float4*)(lds + S_WG + (2*w+1) * 2048 + 1024 + c * 512 + k);
                    const float4 wk = wkv[c * 2 + ii];
                    #pragma unroll
                    for (int b = 0; b < 8; ++b) {
                        const float4 a = *(const float4*)(lds + S_STAGE + b * 512 + k);
                        a0[b] += dot4(w0, a); a1[b] += dot4(w1, a); akv[b] += dot4(wk, a);
                    }
                }
            }
            #pragma unroll
            for (int o = 1; o < 64; o <<= 1)
                #pragma unroll
                for (int b = 0; b < 8; ++b) {
                    a0[b]  += __shfl_xor(a0[b], o);
                    a1[b]  += __shfl_xor(a1[b], o);
                    akv[b] += __shfl_xor(akv[b], o);
                }
            if (l == 0) {
                #pragma unroll
                for (int b = 0; b < 8; ++b) {
                    lds[S_ZX + (2*w)   * 8 + b] = a0[b] + bg0;
                    lds[S_ZX + (2*w+1) * 8 + b] = a1[b] + bg1;
                    lds[S_KVX + w * 8 + b]      = akv[b] + kv_bias;
                }
            }
            __syncthreads();
            if (tid < 128) {                         // coalesced z store
                const int h = tid & 15, b2 = tid >> 4;
                st1(z + (size_t)(g * 8 + b2) * 1024 + hbase + h, lds[S_ZX + h * 8 + b2]);
            } else if (tid < 192 && t > 0) {         // coalesced KV store (sc1)
                const int j = tid - 128;
                const int b2 = j >> 3, hh = j & 7;
                float* dst = kv_mat ? Vb : Kb;
                st1(dst + ((size_t)(t - 1) * 8 + b2) * 1024 + (blk & 127) * 8 + hh,
                    lds[S_KVX + hh * 8 + b2]);
            }
        }
        ++bc; arrive(flags, blk, bc);
        waitbar(flags, golines, bc, blk);   // z (and KV) ready

        // ===== Phase BCD: LN+cell + own-head q-proj + attention (blk<128) =====
        if (blk < 128) {
            {   // stage z[4][ab][1024] — reg-prefetch then store
                float2 zreg[4];
                #pragma unroll
                for (int j = 0; j < 4; ++j) {
                    const int idx = j * 512 + tid;
                    const int g2 = idx >> 9, off2 = idx & 511;
                    zreg[j] = ld2(z + ((size_t)g2 * 8 + ab) * 1024 + off2 * 2);
                }
                #pragma unroll
                for (int j = 0; j < 4; ++j)
                    *(float2*)(lds + S_STAGE + (j * 512 + tid) * 2) = zreg[j];
            }
            __syncthreads();
            const int gt = w >> 1, hf = w & 1;
            float s = 0.f, q2s = 0.f;
            #pragma unroll
            for (int j = 0; j < 8; ++j) {
                const float v = lds[S_STAGE + gt * 1024 + hf * 512 + j * 64 + l];
                s += v; q2s += v * v;
            }
            #pragma unroll
            for (int o = 1; o < 64; o <<= 1) { s += __shfl_xor(s, o); q2s += __shfl_xor(q2s, o); }
            if (l == 0) { lds[S_RED + w] = s; lds[S_R2 + w] = q2s; }
            __syncthreads();
            float mean[4], rstd[4];
            #pragma unroll
            for (int g2 = 0; g2 < 4; ++g2) {
                const float ss = lds[S_RED + 2*g2] + lds[S_RED + 2*g2 + 1];
                const float qq = lds[S_R2  + 2*g2] + lds[S_R2  + 2*g2 + 1];
                const float m = ss * (1.f / 1024.f);
                mean[g2] = m;
                rstd[g2] = rsqrtf(qq * (1.f / 1024.f) - m * m + 1e-5f);
            }
            {   // h = tid
                float zv[4];
                #pragma unroll
                for (int g2 = 0; g2 < 4; ++g2)
                    zv[g2] = (lds[S_STAGE + g2 * 1024 + tid] - mean[g2]) * rstd[g2] * lnw0[g2] + lnb0v[g2];
                const float f  = 1.f / (1.f + __expf(-zv[0]));
                const float ii = 1.f / (1.f + __expf(-zv[1]));
                const float gg = tanhf(zv[2]);
                const float oo = 1.f / (1.f + __expf(-zv[3]));
                const float c  = f * lds[S_CX + tid] + ii * gg;
                lds[S_CX + tid] = c;
                const float ho = oo * tanhf(c);
                lds[S_H0L + tid] = ho;
                if (h0_writer) st1(h0g + ab * 1024 + tid, ho);
            }
            {   // h = tid + 512
                float zv[4];
                #pragma unroll
                for (int g2 = 0; g2 < 4; ++g2)
                    zv[g2] = (lds[S_STAGE + g2 * 1024 + 512 + tid] - mean[g2]) * rstd[g2] * lnw1[g2] + lnb1v[g2];
                const float f  = 1.f / (1.f + __expf(-zv[0]));
                const float ii = 1.f / (1.f + __expf(-zv[1]));
                const float gg = tanhf(zv[2]);
                const float oo = 1.f / (1.f + __expf(-zv[3]));
                const float c  = f * lds[S_CX + 512 + tid] + ii * gg;
                lds[S_CX + 512 + tid] = c;
                const float ho = oo * tanhf(c);
                lds[S_H0L + 512 + tid] = ho;
                if (h0_writer) st1(h0g + ab * 1024 + 512 + tid, ho);
            }
            __syncthreads();
            {   // q-proj for own head: 64 rows, streamed Wq (L2-resident)
                const float* wrow = Wq + (size_t)(anh * 64 + qdh) * 1024;
                float qa = 0.f;
                #pragma unroll 8
                for (int j = 0; j < 32; ++j) {
                    const int k = j * 32 + qks * 4;
                    qa += dot4(*(const float4*)(wrow + k), *(const float4*)(lds + S_H0L + k));
                }
                qa += __shfl_xor(qa, 1); qa += __shfl_xor(qa, 2); qa += __shfl_xor(qa, 4);
                if (qks == 0) lds[S_Q + qdh] = (qa + q_bias) * 0.125f;
            }
            __syncthreads();
            if (t > 0) {
                // QK: scatter per-position, NORMAL cached K loads (L2-resident)
                float sc = -1e30f;
                if (tid < t) {
                    const float* kr = Kb + ((size_t)tid * 8 + ab) * 1024 + anh * 64;
                    float d = 0.f;
                    #pragma unroll
                    for (int j = 0; j < 16; ++j) {
                        const float4 k4 = *(const float4*)(kr + j * 4);
                        d += k4.x*lds[S_Q + j*4]   + k4.y*lds[S_Q + j*4+1]
                           + k4.z*lds[S_Q + j*4+2] + k4.w*lds[S_Q + j*4+3];
                    }
                    sc = d;
                }
                float mx = sc;
                #pragma unroll
                for (int o = 1; o < 64; o <<= 1) mx = fmaxf(mx, __shfl_xor(mx, o));
                if (l == 0) lds[S_RED + w] = mx;
                __syncthreads();
                mx = lds[S_RED];
                #pragma unroll
                for (int j = 1; j < 8; ++j) mx = fmaxf(mx, lds[S_RED + j]);
                const float p = (tid < t) ? __expf(sc - mx) : 0.f;
                if (tid < 256) lds[S_PS + tid] = p;
                float ps = p;
                #pragma unroll
                for (int o = 1; o < 64; o <<= 1) ps += __shfl_xor(ps, o);
                if (l == 0) lds[S_R2 + w] = ps;
                __syncthreads();
                float tot = lds[S_R2];
                #pragma unroll
                for (int j = 1; j < 8; ++j) tot += lds[S_R2 + j];
                const float inv = 1.f / tot;
                // PV: 4x unrolled, dual accumulators, NORMAL cached V loads
                const int dh2 = tid & 31, ss2 = tid >> 5;
                const float* vbase = Vb + (size_t)ab * 1024 + anh * 64 + dh2 * 2;
                float cax0 = 0.f, cay0 = 0.f, cax1 = 0.f, cay1 = 0.f;
                int s2 = ss2;
                for (; s2 + 48 < t; s2 += 64) {
                    const float2 va = *(const float2*)(vbase + (size_t)(s2)      * 8192);
                    const float2 vb = *(const float2*)(vbase + (size_t)(s2 + 16) * 8192);
                    const float2 vc = *(const float2*)(vbase + (size_t)(s2 + 32) * 8192);
                    const float2 vd = *(const float2*)(vbase + (size_t)(s2 + 48) * 8192);
                    const float pa = lds[S_PS + s2],      pb = lds[S_PS + s2 + 16];
                    const float pc = lds[S_PS + s2 + 32], pd = lds[S_PS + s2 + 48];
                    cax0 += pa * va.x; cay0 += pa * va.y;
                    cax1 += pb * vb.x; cay1 += pb * vb.y;
                    cax0 += pc * vc.x; cay0 += pc * vc.y;
                    cax1 += pd * vd.x; cay1 += pd * vd.y;
                }
                for (; s2 < t; s2 += 16) {
                    const float pp = lds[S_PS + s2];
                    const float2 v2 = *(const float2*)(vbase + (size_t)s2 * 8192);
                    cax0 += pp * v2.x; cay0 += pp * v2.y;
                }
                *(float2*)(lds + S_STAGE + tid * 2) = make_float2(cax0 + cax1, cay0 + cay1);
                __syncthreads();
                if (tid < 64) {
                    float v = 0.f;
                    #pragma unroll
                    for (int j = 0; j < 16; ++j) v += lds[S_STAGE + j * 64 + tid];
                    st1(ctx + ab * 1024 + anh * 64 + tid, v * inv);
                }
            }
            // producer flag: ctx[ab][anh] (and h0g for anh==0) drained by syncthreads
            __syncthreads();
            if (tid == 0) stu(cflg + blk * 16, (unsigned)(t + 1));
        }

        // ===== E wait: poll the 32 producer flags for batches eb0, eb1 =====
        {
            if (tid < 32) {
                const int pb = (tid < 16) ? eb0 : eb1;
                const unsigned* f = cflg + (pb * 16 + (tid & 15)) * 16;
                while (ldu(f) < (unsigned)(t + 1)) __builtin_amdgcn_s_sleep(2);
            }
            __syncthreads();
        }

        // ===== Phase E: out-proj (16 rows x 2 batches, direct ctx reads) =====
        {
            if (tid < 16) {     // h0 slice: [2 b][16 r] into S_EH
                const int bsel = tid >> 3, hp = tid & 7;
                *(float2*)(lds + S_EH + bsel * 16 + hp * 2) =
                    ld2(h0g + (size_t)(eb0 + bsel) * 1024 + rg * 16 + hp * 2);
            }
            float o00 = 0.f, o01 = 0.f, o10 = 0.f, o11 = 0.f;  // row(2) x batch(2)
            if (t > 0) {
                float4 c0r[4], c1r[4];
                #pragma unroll
                for (int i = 0; i < 4; ++i) {
                    const int k = i * 256 + l * 4;
                    c0r[i] = ld4(ctx + (size_t)eb0 * 1024 + k);
                    c1r[i] = ld4(ctx + (size_t)eb1 * 1024 + k);
                }
                #pragma unroll
                for (int i = 0; i < 4; ++i) {
                    const int k = i * 256 + l * 4;
                    const float4 w0 = *(const float4*)(Wo + (size_t)er0 * 1024 + k);
                    const float4 w1 = *(const float4*)(Wo + (size_t)(er0+1) * 1024 + k);
                    o00 += dot4(w0, c0r[i]); o01 += dot4(w0, c1r[i]);
                    o10 += dot4(w1, c0r[i]); o11 += dot4(w1, c1r[i]);
                }
                #pragma unroll
                for (int o = 1; o < 64; o <<= 1) {
                    o00 += __shfl_xor(o00, o); o01 += __shfl_xor(o01, o);
                    o10 += __shfl_xor(o10, o); o11 += __shfl_xor(o11, o);
                }
            }
            __syncthreads();
            if (l == 0) {
                const float h00 = lds[S_EH + 2*w],      h10 = lds[S_EH + 2*w + 1];
                const float h01 = lds[S_EH + 16 + 2*w], h11 = lds[S_EH + 16 + 2*w + 1];
                const float v00 = (t > 0) ? h00 + o00 + bor0 : h00;
                const float v10 = (t > 0) ? h10 + o10 + bor1 : h10;
                const float v01 = (t > 0) ? h01 + o01 + bor0 : h01;
                const float v11 = (t > 0) ? h11 + o11 + bor1 : h11;
                st2(hx + eb0 * 1024 + er0, make_float2(v00, v10));
                st2(hx + eb1 * 1024 + er0, make_float2(v01, v11));
                *(float2*)(out + (size_t)t * 8192 + eb0 * 1024 + er0) = make_float2(v00, v10);
                *(float2*)(out + (size_t)t * 8192 + eb1 * 1024 + er0) = make_float2(v01, v11);
            }
        }
        ++bc; arrive(flags, blk, bc);       // hx(t) ready (waited at top of t+1)
    }
    waitbar(flags, golines, bc, blk);

    // epilogue: final cx (replicas) and hx
    if (h0_writer) {
        out[2097152 + 8192 + ab * 1024 + tid]       = lds[S_CX + tid];
        out[2097152 + 8192 + ab * 1024 + 512 + tid] = lds[S_CX + 512 + tid];
    }
    if (blk >= 136 && blk < 144) {
        const int b = blk - 136;
        out[2097152 + b * 1024 + tid]       = ld1(hx + b * 1024 + tid);
        out[2097152 + b * 1024 + 512 + tid] = ld1(hx + b * 1024 + 512 + tid);
    }
}

extern "C" void kernel_launch(void* const* d_in, const int* in_sizes, int n_in,
                              void* d_out, int out_size, void* d_ws, size_t ws_size,
                              hipStream_t stream) {
    const float* x   = (const float*)d_in[0];
    const float* Wg  = (const float*)d_in[1];
    const float* bg  = (const float*)d_in[2];
    const float* lng = (const float*)d_in[3];
    const float* lnb = (const float*)d_in[4];
    const float* Wq  = (const float*)d_in[5];
    const float* Wk  = (const float*)d_in[6];
    const float* Wv  = (const float*)d_in[7];
    const float* bq  = (const float*)d_in[8];
    const float* bk  = (const float*)d_in[9];
    const float* bv  = (const float*)d_in[10];
    const float* Wo  = (const float*)d_in[11];
    const float* bo  = (const float*)d_in[12];
    float* out = (float*)d_out;
    float* ws  = (float*)d_ws;

    static int attr_set = 0;
    if (!attr_set) {
        hipFuncSetAttribute((const void*)qlstm_kernel,
                            hipFuncAttributeMaxDynamicSharedMemorySize, LDS_BYTES);
        attr_set = 1;
    }
    // zero flags + go lines + ctx flags (graph-captured; deterministic per replay)
    hipMemsetAsync((char*)d_ws + (size_t)OFF_FLAGS * 4, 0, (size_t)FLG_U32 * 4, stream);

    void* args[] = { &x, &Wg, &bg, &lng, &lnb, &Wq, &Wk, &Wv,
                     &bq, &bk, &bv, &Wo, &bo, &out, &ws };
    hipLaunchCooperativeKernel((void*)qlstm_kernel, dim3(NBLK), dim3(NTHR),
                               args, LDS_BYTES, stream);
}